// Round 16
// baseline (131.854 us; speedup 1.0000x reference)
//
#include <hip/hip_runtime.h>
#include <hip/hip_cooperative_groups.h>

namespace cg = cooperative_groups;

#define T_STEPS 50000
#define HID     512
#define LBASE   512
#define CHUNKS  98             // ceil(50000/512); tail chunk = 336 steps
#define SDMAX   (2 * LBASE)    // warmup(512) + output(512) float4 = 16384 B LDS

static_assert((T_STEPS + LBASE - 1) / LBASE == CHUNKS, "chunk count");
static_assert(LBASE % 16 == 0, "16-step bodies");

#define PIN2D(a) asm volatile("" : "+v"(a.x), "+v"(a.y))

// ---------------------------------------------------------------------------
// One recurrence step (~18 VALU), math unchanged (validated absmax 0.25).
// ---------------------------------------------------------------------------
#define STEP(P, TT, PE, QV)                                                   \
    {                                                                         \
        const float dfdt = fmaf(DF, (TT), ndftmx);                            \
        const float melt = __builtin_amdgcn_fmed3f(dfdt, s0, 0.0f);           \
        const float ps   = ((TT) <= TMN) ? (P) : 0.0f;                        \
        const float w    = melt - ps;                                         \
        s0 = s0 - w;                                                          \
        const float qs   = fmaxf(s1 - SM, 0.0f);                              \
        const float m    = fminf(s1, SM);                                     \
        const float u    = fmaf(g, s1, qc);                                   \
        const float qb   = fminf(QM, __builtin_amdgcn_exp2f(u));              \
        const float npei = (PE)*ninv_sm;                                      \
        const float A    = (s1 + ((P) + w)) - qs;                             \
        const float B    = fmaf(m, npei, A);                                  \
        s1 = fmaxf(B - qb, 0.0f);                                             \
        QV = qb + qs;                                                         \
    }

// ---------------------------------------------------------------------------
// Fused cooperative kernel. Block b -> chunk c = b>>1, units h in
// [(b&1)*256, (b&1)*256+256). Grid = 196 blocks x 256 thr (co-resident).
//
// Phase A: compute pet from x directly into the block's LDS span
//          [start, cE) (start = cL-LBASE for c>=1; chunk 0: [0,512)).
//          Replaces the pack kernel + ptp workspace + agg restaging.
// Phase B: Lindley aggregate (D,M) over the output span -> dm.   grid.sync()
// Phase C: blocks 0-1 compose the 98 maps (depth-4 pipeline, r15-validated)
//          -> exact s0 at every boundary in s0b.                 grid.sync()
// Phase D: r15-validated chunk scan from the SAME LDS image: 512 warmup
//          steps (s1 contraction; s0 exact from s0b) + 512 output steps.
// ---------------------------------------------------------------------------
__global__ __launch_bounds__(256)
void hydro_fused_kernel(const float* __restrict__ x,
                        const float* __restrict__ f_,
                        const float* __restrict__ smax_,
                        const float* __restrict__ qmax_,
                        const float* __restrict__ df_,
                        const float* __restrict__ tmax_,
                        const float* __restrict__ tmin_,
                        double2*     __restrict__ dm,
                        float*       __restrict__ s0b,
                        float*       __restrict__ q) {
    __shared__ float4 sd[SDMAX];
    cg::grid_group grid = cg::this_grid();

    const int b     = blockIdx.x;          // 0..CHUNKS*2-1
    const int chunk = b >> 1;
    const int h     = ((b & 1) << 8) | (int)threadIdx.x;

    const float F   = f_[h];
    const float SM  = smax_[h];
    const float QM  = qmax_[h];
    const float DF  = df_[h];
    const float TMX = tmax_[h];
    const float TMN = tmin_[h];

    const float g       = F * 1.4426950408889634f;   // f * log2(e)
    const float qc      = __log2f(QM) - g * SM;       // log2(qmax) - g*smax
    const float ninv_sm = -1.0f / SM;
    const float ndftmx  = -(DF * TMX);

    const int cL    = chunk * LBASE;
    const int cE    = (cL + LBASE < T_STEPS) ? (cL + LBASE) : T_STEPS;
    const int start = (chunk >= 1) ? (cL - LBASE) : 0;   // boundary-aligned
    const int n     = cE - start;          // 512 (chunk 0), 1024, or 848 tail

    // ---- Phase A: pet into LDS straight from x (x is 600 KB, L2-resident).
    for (int i = threadIdx.x; i < n; i += 256) {
        const int t = start + i;
        const float p  = x[3 * t + 0];
        const float tt = x[3 * t + 1];
        const float ld = x[3 * t + 2];
        const float esat = 0.611f * __expf(17.3f * tt / (tt + 237.3f));
        const float pe   = 29.8f * (ld * 24.0f) * esat / (tt + 273.2f);
        sd[i] = make_float4(p, tt, pe, 0.f);
    }
    __syncthreads();

    // ---- Phase B: Lindley aggregate over the OUTPUT span.
    const int wbase = cL - start;                     // 0 or 512
    {
        double D = 0.0, M = -1.0e300;
        const int n16 = (cE - cL) >> 4;               // 32, or 21 for tail
        for (int it = 0; it < n16; ++it) {
            const int base = wbase + it * 16;
#pragma unroll
            for (int i = 0; i < 16; ++i) {
                const float4 v = sd[base + i];
                const float cap = fmaxf(fmaf(DF, v.y, ndftmx), 0.0f);
                const float ps  = (v.y <= TMN) ? v.x : 0.0f;
                const double d  = (double)ps - (double)cap;
                D += d;
                M = fmax(M + d, (double)ps);
            }
        }
        dm[chunk * HID + h] = make_double2(D, M);
    }
    grid.sync();

    // ---- Phase C: blocks 0-1 compose the 98 chunk maps -> exact s0b.
    // Depth-4 rotating prefetch (r15-validated). Over-reads dm to index ~100
    // -> lands in the adjacent s0b region of the same workspace (unused).
    if (b < 2) {
        const int h2 = (b << 8) | (int)threadIdx.x;
        const double2* dp = dm + h2;
        double xv = 0.0;
        s0b[h2] = 0.0f;                               // boundary 0: s0 = 0
#define COMP(a, c)                                                            \
        {                                                                     \
            PIN2D(a);                                                         \
            xv = fmax(xv + a.x, a.y);                                         \
            s0b[(size_t)((c) + 1) * HID + h2] = (float)xv;                    \
        }
        double2 p0 = dp[0];
        double2 p1 = dp[(size_t)1 * HID];
        double2 p2 = dp[(size_t)2 * HID];
        double2 p3 = dp[(size_t)3 * HID];
        COMP(p0, 0);
        p0 = dp[(size_t)4 * HID];
        for (int j = 0; j < 24; ++j) {
            const int c = 1 + 4 * j;
            COMP(p1, c);     p1 = dp[(size_t)(c + 4) * HID];
            COMP(p2, c + 1); p2 = dp[(size_t)(c + 5) * HID];
            COMP(p3, c + 2); p3 = dp[(size_t)(c + 6) * HID];
            COMP(p0, c + 3); p0 = dp[(size_t)(c + 7) * HID];
        }
#undef COMP
    }
    grid.sync();

    // ---- Phase D: chunk scan from the same LDS image.
    float s0 = (chunk >= 1) ? s0b[(chunk - 1) * HID + h] : 0.0f;
    float s1 = 0.0f;

    const int nWarm16 = wbase >> 4;                   // 0 or 32
    for (int it = 0; it < nWarm16; ++it) {
        const int base = it * 16;
        float qv;
#pragma unroll
        for (int i = 0; i < 16; ++i) {
            const float4 v = sd[base + i];
            STEP(v.x, v.y, v.z, qv);
        }
        (void)qv;
    }

    char* qbase  = (char*)q;
    unsigned off = (unsigned)cL * 2048u + (unsigned)h * 4u;

    const int nOut16 = (cE - cL) >> 4;                // 32, or 21 for tail
    for (int it = 0; it < nOut16; ++it) {
        const int base = wbase + it * 16;
#pragma unroll
        for (int i = 0; i < 16; ++i) {
            const float4 v = sd[base + i];
            float qv;
            STEP(v.x, v.y, v.z, qv);
            *(float*)(qbase + off + (unsigned)i * 2048u) = qv;
        }
        off += 32768u;
    }
}

// ---------------------------------------------------------------------------
// Fallback: full-serial scan (correct for any ws_size), pet inline.
// ---------------------------------------------------------------------------
__global__ __launch_bounds__(64)
void hydro_serial_kernel(const float* __restrict__ x,
                         const float* __restrict__ f_,
                         const float* __restrict__ smax_,
                         const float* __restrict__ qmax_,
                         const float* __restrict__ df_,
                         const float* __restrict__ tmax_,
                         const float* __restrict__ tmin_,
                         float* __restrict__ q) {
    const int h = blockIdx.x * 64 + threadIdx.x;
    const float F = f_[h], SM = smax_[h], QM = qmax_[h];
    const float DF = df_[h], TMX = tmax_[h], TMN = tmin_[h];
    const float g       = F * 1.4426950408889634f;
    const float qc      = __log2f(QM) - g * SM;
    const float ninv_sm = -1.0f / SM;
    const float ndftmx  = -(DF * TMX);
    float s0 = 0.f, s1 = 0.f;
    for (int t = 0; t < T_STEPS; ++t) {
        const float p  = x[3 * t + 0];
        const float tt = x[3 * t + 1];
        const float ld = x[3 * t + 2];
        const float esat = 0.611f * __expf(17.3f * tt / (tt + 237.3f));
        const float pe   = 29.8f * (ld * 24.0f) * esat / (tt + 273.2f);
        float qv;
        STEP(p, tt, pe, qv);
        q[(size_t)t * HID + h] = qv;
    }
}

// ---------------------------------------------------------------------------
extern "C" void kernel_launch(void* const* d_in, const int* in_sizes, int n_in,
                              void* d_out, int out_size, void* d_ws,
                              size_t ws_size, hipStream_t stream) {
    const float* x    = (const float*)d_in[0];
    const float* f    = (const float*)d_in[1];
    const float* smax = (const float*)d_in[2];
    const float* qmax = (const float*)d_in[3];
    const float* df   = (const float*)d_in[4];
    const float* tmax = (const float*)d_in[5];
    const float* tmin = (const float*)d_in[6];
    float* q = (float*)d_out;

    const size_t DM_BYTES  = (size_t)CHUNKS * HID * sizeof(double2); // ~784 KB
    const size_t S0B_OFF   = DM_BYTES;
    const size_t S0B_BYTES = (size_t)CHUNKS * HID * sizeof(float);   // ~196 KB
    const size_t NEED      = S0B_OFF + S0B_BYTES + 65536;            // scan pad

    if (ws_size >= NEED) {
        double2* dm  = (double2*)d_ws;
        float*   s0b = (float*)((char*)d_ws + S0B_OFF);

        void* args[] = {(void*)&x, (void*)&f, (void*)&smax, (void*)&qmax,
                        (void*)&df, (void*)&tmax, (void*)&tmin,
                        (void*)&dm, (void*)&s0b, (void*)&q};
        hipLaunchCooperativeKernel((void*)hydro_fused_kernel,
                                   dim3(CHUNKS * 2), dim3(256),
                                   args, 0, stream);
    } else {
        hydro_serial_kernel<<<HID / 64, 64, 0, stream>>>(
            x, f, smax, qmax, df, tmax, tmin, q);
    }
}

// Round 17
// 113.523 us; speedup vs baseline: 1.1615x; 1.1615x over previous
//
#include <hip/hip_runtime.h>

#define T_STEPS 50000
#define HID     512
#define LBASE   128
#define CHUNKS  391            // ceil(50000/128); tail chunk = 80 steps
#define WARMCH  3              // warm = 384 steps (validated r6: absmax 0.25)
#define WARM    (WARMCH * LBASE)
#define SDMAX   (WARM + LBASE) // 512 float4 = 8192 B LDS

static_assert((T_STEPS + LBASE - 1) / LBASE == CHUNKS, "chunk count");
static_assert(LBASE % 16 == 0 && WARM % 16 == 0, "16-step bodies");
static_assert((CHUNKS - 1) == 97 * 4 + 2, "scan rotation layout");

#define PIN2D(a) asm volatile("" : "+v"(a.x), "+v"(a.y))

// pet from raw x row (scalar loads; x is 600 KB -> L2-resident after 1st use)
#define PET_FROM_X(t, P, TT, PE)                                              \
    const float P  = x[3 * (t) + 0];                                          \
    const float TT = x[3 * (t) + 1];                                          \
    const float ld_##P = x[3 * (t) + 2];                                      \
    const float esat_##P = 0.611f * __expf(17.3f * TT / (TT + 237.3f));       \
    const float PE = 29.8f * (ld_##P * 24.0f) * esat_##P / (TT + 273.2f);

// ---------------------------------------------------------------------------
// Pass A: snow bucket is max-plus linear (Lindley): s0' = max(s0 + d, ps),
// d = ps - cap, cap = max(df*(t-tmax), 0). Segment (D, M) composes as
// x -> max(x + D, M). Block = chunk x 256 units; pet computed inline into
// LDS (replaces the pack kernel), then broadcast ds_read_b128 loop.
// ---------------------------------------------------------------------------
__global__ __launch_bounds__(256)
void lindley_agg_kernel(const float* __restrict__ x,
                        const float* __restrict__ df_,
                        const float* __restrict__ tmax_,
                        const float* __restrict__ tmin_,
                        double2* __restrict__ dm) {
    __shared__ float4 sd[LBASE];
    const int b     = blockIdx.x;          // 0..CHUNKS*2-1
    const int chunk = b >> 1;
    const int h     = ((b & 1) << 8) | (int)threadIdx.x;

    const float DF = df_[h], TMX = tmax_[h], TMN = tmin_[h];
    const float ndftmx = -(DF * TMX);

    const int cL = chunk * LBASE;
    const int cE = (cL + LBASE < T_STEPS) ? (cL + LBASE) : T_STEPS;
    const int n  = cE - cL;                // 128, or 80 for tail

    for (int i = threadIdx.x; i < n; i += 256) {
        PET_FROM_X(cL + i, p, tt, pe);
        sd[i] = make_float4(p, tt, pe, 0.f);
    }
    __syncthreads();

    double D = 0.0, M = -1.0e300;
    const int n16 = n >> 4;                // 8, or 5 for tail
    for (int it = 0; it < n16; ++it) {
        const int base = it * 16;
#pragma unroll
        for (int i = 0; i < 16; ++i) {
            const float4 v = sd[base + i];
            const float cap = fmaxf(fmaf(DF, v.y, ndftmx), 0.0f);
            const float ps  = (v.y <= TMN) ? v.x : 0.0f;
            const double d  = (double)ps - (double)cap;
            D += d;
            M = fmax(M + d, (double)ps);
        }
    }
    dm[chunk * HID + h] = make_double2(D, M);
}

// ---------------------------------------------------------------------------
// Pass B: compose the 391 chunk maps sequentially per unit -> EXACT s0 at
// every boundary. Depth-4 rotating prefetch (r15-validated pattern).
// 390 composes = 97*4 + 2. Over-reads dm by one row (index 391) -> lands in
// the adjacent s0b region of the same workspace allocation (unused, no fault).
// ---------------------------------------------------------------------------
__global__ __launch_bounds__(64)
void lindley_scan_kernel(const double2* __restrict__ dm,
                         float* __restrict__ s0b) {
    const int h = blockIdx.x * 64 + threadIdx.x;   // grid = 8 blocks
    const double2* dp = dm + h;
    double xv = 0.0;
    s0b[h] = 0.0f;                                  // boundary 0: s0 = 0

#define COMP(a, c)                                                            \
    {                                                                         \
        PIN2D(a);                                                             \
        xv = fmax(xv + a.x, a.y);                                             \
        s0b[(size_t)((c) + 1) * HID + h] = (float)xv;                         \
    }
#define COMPS(PJ, c)                                                          \
    { COMP(PJ, c); PJ = dp[(size_t)((c) + 4) * HID]; }

    double2 p0 = dp[0];
    double2 p1 = dp[(size_t)1 * HID];
    double2 p2 = dp[(size_t)2 * HID];
    double2 p3 = dp[(size_t)3 * HID];

    for (int j = 0; j < 97; ++j) {                  // composes 0..387
        const int c = 4 * j;
        COMPS(p0, c);
        COMPS(p1, c + 1);
        COMPS(p2, c + 2);
        COMPS(p3, c + 3);                           // j=96 reloads dm[391]: pad
    }
    COMP(p0, 388);
    COMP(p1, 389);                                  // boundary 390 written
#undef COMPS
#undef COMP
}

// ---------------------------------------------------------------------------
// One recurrence step (~18 VALU), math unchanged (validated absmax 0.25).
// ---------------------------------------------------------------------------
#define STEP(P, TT, PE, QV)                                                   \
    {                                                                         \
        const float dfdt = fmaf(DF, (TT), ndftmx);                            \
        const float melt = __builtin_amdgcn_fmed3f(dfdt, s0, 0.0f);           \
        const float ps   = ((TT) <= TMN) ? (P) : 0.0f;                        \
        const float w    = melt - ps;                                         \
        s0 = s0 - w;                                                          \
        const float qs   = fmaxf(s1 - SM, 0.0f);                              \
        const float m    = fminf(s1, SM);                                     \
        const float u    = fmaf(g, s1, qc);                                   \
        const float qb   = fminf(QM, __builtin_amdgcn_exp2f(u));              \
        const float npei = (PE)*ninv_sm;                                      \
        const float A    = (s1 + ((P) + w)) - qs;                             \
        const float B    = fmaf(m, npei, A);                                  \
        s1 = fmaxf(B - qb, 0.0f);                                             \
        QV = qb + qs;                                                         \
    }

// ---------------------------------------------------------------------------
// Main chunked scan, LDS-staged, SHORT CHUNKS. wall = (WARM+LBASE) x C_step
// and every chunk-wave runs in parallel: 384+128 = 512 steps/wave (was 1024).
// 782 blocks ~ 3/CU = 3 waves/SIMD: issue (~3x40cy) sits at the latency knee
// (~117cy measured r16), hiding LDS-read latency. ALIGNMENT INVARIANT: warm
// span = WARMCH*LBASE exactly, so s0b[chunk-WARMCH] (exact s0 at t=start) is
// applied at start. Chunks 0..2 start at t=0 (fully exact). Validated r6.
// ---------------------------------------------------------------------------
__global__ __launch_bounds__(256)
void hydro_chunk_kernel(const float* __restrict__ x,
                        const float* __restrict__ s0b,
                        const float* __restrict__ f_,
                        const float* __restrict__ smax_,
                        const float* __restrict__ qmax_,
                        const float* __restrict__ df_,
                        const float* __restrict__ tmax_,
                        const float* __restrict__ tmin_,
                        float*       __restrict__ q) {
    __shared__ float4 sd[SDMAX];
    const int b     = blockIdx.x;          // 0..CHUNKS*2-1
    const int chunk = b >> 1;
    const int h     = ((b & 1) << 8) | (int)threadIdx.x;

    const float F   = f_[h];
    const float SM  = smax_[h];
    const float QM  = qmax_[h];
    const float DF  = df_[h];
    const float TMX = tmax_[h];
    const float TMN = tmin_[h];

    const float g       = F * 1.4426950408889634f;   // f * log2(e)
    const float qc      = __log2f(QM) - g * SM;       // log2(qmax) - g*smax
    const float ninv_sm = -1.0f / SM;
    const float ndftmx  = -(DF * TMX);

    const int cL    = chunk * LBASE;
    const int cE    = (cL + LBASE < T_STEPS) ? (cL + LBASE) : T_STEPS;
    const int start = (chunk >= WARMCH) ? (cL - WARM) : 0;  // boundary-aligned
    const int n     = cE - start;

    for (int i = threadIdx.x; i < n; i += 256) {
        PET_FROM_X(start + i, p, tt, pe);
        sd[i] = make_float4(p, tt, pe, 0.f);
    }
    __syncthreads();

    float s0 = (chunk >= WARMCH) ? s0b[(chunk - WARMCH) * HID + h] : 0.0f;
    float s1 = 0.0f;

    const int nWarm16 = (cL - start) >> 4;            // 0, 8, 16, or 24
    for (int it = 0; it < nWarm16; ++it) {
        const int base = it * 16;
        float qv;
#pragma unroll
        for (int i = 0; i < 16; ++i) {
            const float4 v = sd[base + i];
            STEP(v.x, v.y, v.z, qv);
        }
        (void)qv;
    }

    char* qbase  = (char*)q;
    unsigned off = (unsigned)cL * 2048u + (unsigned)h * 4u;
    const int wbase = cL - start;                     // 0..384

    const int nOut16 = (cE - cL) >> 4;                // 8, or 5 for tail
    for (int it = 0; it < nOut16; ++it) {
        const int base = wbase + it * 16;
#pragma unroll
        for (int i = 0; i < 16; ++i) {
            const float4 v = sd[base + i];
            float qv;
            STEP(v.x, v.y, v.z, qv);
            *(float*)(qbase + off + (unsigned)i * 2048u) = qv;
        }
        off += 32768u;
    }
}

// ---------------------------------------------------------------------------
// Fallback: full-serial scan (correct for any ws_size), pet inline.
// ---------------------------------------------------------------------------
__global__ __launch_bounds__(64)
void hydro_serial_kernel(const float* __restrict__ x,
                         const float* __restrict__ f_,
                         const float* __restrict__ smax_,
                         const float* __restrict__ qmax_,
                         const float* __restrict__ df_,
                         const float* __restrict__ tmax_,
                         const float* __restrict__ tmin_,
                         float* __restrict__ q) {
    const int h = blockIdx.x * 64 + threadIdx.x;
    const float F = f_[h], SM = smax_[h], QM = qmax_[h];
    const float DF = df_[h], TMX = tmax_[h], TMN = tmin_[h];
    const float g       = F * 1.4426950408889634f;
    const float qc      = __log2f(QM) - g * SM;
    const float ninv_sm = -1.0f / SM;
    const float ndftmx  = -(DF * TMX);
    float s0 = 0.f, s1 = 0.f;
    for (int t = 0; t < T_STEPS; ++t) {
        PET_FROM_X(t, p, tt, pe);
        float qv;
        STEP(p, tt, pe, qv);
        q[(size_t)t * HID + h] = qv;
    }
}

// ---------------------------------------------------------------------------
extern "C" void kernel_launch(void* const* d_in, const int* in_sizes, int n_in,
                              void* d_out, int out_size, void* d_ws,
                              size_t ws_size, hipStream_t stream) {
    const float* x    = (const float*)d_in[0];
    const float* f    = (const float*)d_in[1];
    const float* smax = (const float*)d_in[2];
    const float* qmax = (const float*)d_in[3];
    const float* df   = (const float*)d_in[4];
    const float* tmax = (const float*)d_in[5];
    const float* tmin = (const float*)d_in[6];
    float* q = (float*)d_out;

    const size_t DM_BYTES  = (size_t)CHUNKS * HID * sizeof(double2); // ~3.2 MB
    const size_t S0B_OFF   = DM_BYTES;
    const size_t S0B_BYTES = (size_t)CHUNKS * HID * sizeof(float);   // ~800 KB
    const size_t NEED      = S0B_OFF + S0B_BYTES + 65536;            // scan pad

    if (ws_size >= NEED) {
        double2* dm  = (double2*)d_ws;
        float*   s0b = (float*)((char*)d_ws + S0B_OFF);

        lindley_agg_kernel<<<CHUNKS * 2, 256, 0, stream>>>(x, df, tmax, tmin, dm);
        lindley_scan_kernel<<<HID / 64, 64, 0, stream>>>(dm, s0b);
        hydro_chunk_kernel<<<CHUNKS * 2, 256, 0, stream>>>(
            x, s0b, f, smax, qmax, df, tmax, tmin, q);
    } else {
        hydro_serial_kernel<<<HID / 64, 64, 0, stream>>>(
            x, f, smax, qmax, df, tmax, tmin, q);
    }
}

// Round 18
// 87.816 us; speedup vs baseline: 1.5015x; 1.2927x over previous
//
#include <hip/hip_runtime.h>

#define T_STEPS 50000
#define HID     512
#define LBASE   256
#define CHUNKS  196            // ceil(50000/256); tail chunk = 80 steps
#define WARMCH  2              // warm = 512 steps (validated r5/r9/r15)
#define WARM    (WARMCH * LBASE)
#define SDMAX   (WARM + LBASE) // 768 float4 = 12288 B LDS

static_assert((T_STEPS + LBASE - 1) / LBASE == CHUNKS, "chunk count");
static_assert(LBASE % 16 == 0 && WARM % 16 == 0, "16-step bodies");
static_assert((CHUNKS - 1) == 48 * 4 + 3, "scan rotation layout");

#define PIN2D(a) asm volatile("" : "+v"(a.x), "+v"(a.y))

// pet from raw x row (x is 600 KB -> L2-resident after first touch)
#define PET_FROM_X(t, P, TT, PE)                                              \
    const float P  = x[3 * (t) + 0];                                          \
    const float TT = x[3 * (t) + 1];                                          \
    const float ld_##P = x[3 * (t) + 2];                                      \
    const float esat_##P = 0.611f * __expf(17.3f * TT / (TT + 237.3f));       \
    const float PE = 29.8f * (ld_##P * 24.0f) * esat_##P / (TT + 273.2f);

// ---------------------------------------------------------------------------
// Pass A: snow bucket is max-plus linear (Lindley): s0' = max(s0 + d, ps),
// d = ps - cap, cap = max(df*(t-tmax), 0). Segment (D, M) composes as
// x -> max(x + D, M). Block = chunk x 256 units; pet inline into LDS.
// ---------------------------------------------------------------------------
__global__ __launch_bounds__(256)
void lindley_agg_kernel(const float* __restrict__ x,
                        const float* __restrict__ df_,
                        const float* __restrict__ tmax_,
                        const float* __restrict__ tmin_,
                        double2* __restrict__ dm) {
    __shared__ float4 sd[LBASE];
    const int b     = blockIdx.x;          // 0..CHUNKS*2-1
    const int chunk = b >> 1;
    const int h     = ((b & 1) << 8) | (int)threadIdx.x;

    const float DF = df_[h], TMX = tmax_[h], TMN = tmin_[h];
    const float ndftmx = -(DF * TMX);

    const int cL = chunk * LBASE;
    const int cE = (cL + LBASE < T_STEPS) ? (cL + LBASE) : T_STEPS;
    const int n  = cE - cL;                // 256, or 80 for tail

    for (int i = threadIdx.x; i < n; i += 256) {
        PET_FROM_X(cL + i, p, tt, pe);
        sd[i] = make_float4(p, tt, pe, 0.f);
    }
    __syncthreads();

    double D = 0.0, M = -1.0e300;
    const int n16 = n >> 4;                // 16, or 5 for tail
    for (int it = 0; it < n16; ++it) {
        const int base = it * 16;
#pragma unroll
        for (int i = 0; i < 16; ++i) {
            const float4 v = sd[base + i];
            const float cap = fmaxf(fmaf(DF, v.y, ndftmx), 0.0f);
            const float ps  = (v.y <= TMN) ? v.x : 0.0f;
            const double d  = (double)ps - (double)cap;
            D += d;
            M = fmax(M + d, (double)ps);
        }
    }
    dm[chunk * HID + h] = make_double2(D, M);
}

// ---------------------------------------------------------------------------
// Pass B: compose the 196 chunk maps sequentially per unit -> EXACT s0 at
// every boundary. Depth-4 rotating prefetch; 195 composes = 48*4 + 3, so the
// loop's reloads stop exactly at dm[195] (no over-read).
// ---------------------------------------------------------------------------
__global__ __launch_bounds__(64)
void lindley_scan_kernel(const double2* __restrict__ dm,
                         float* __restrict__ s0b) {
    const int h = blockIdx.x * 64 + threadIdx.x;   // grid = 8 blocks
    const double2* dp = dm + h;
    double xv = 0.0;
    s0b[h] = 0.0f;                                  // boundary 0: s0 = 0

#define COMP(a, c)                                                            \
    {                                                                         \
        PIN2D(a);                                                             \
        xv = fmax(xv + a.x, a.y);                                             \
        s0b[(size_t)((c) + 1) * HID + h] = (float)xv;                         \
    }
#define COMPS(PJ, c)                                                          \
    { COMP(PJ, c); PJ = dp[(size_t)((c) + 4) * HID]; }

    double2 p0 = dp[0];
    double2 p1 = dp[(size_t)1 * HID];
    double2 p2 = dp[(size_t)2 * HID];
    double2 p3 = dp[(size_t)3 * HID];

    for (int j = 0; j < 48; ++j) {                  // composes 0..191
        const int c = 4 * j;
        COMPS(p0, c);
        COMPS(p1, c + 1);
        COMPS(p2, c + 2);
        COMPS(p3, c + 3);                           // j=47 reloads dm[195]: ok
    }
    COMP(p0, 192);
    COMP(p1, 193);
    COMP(p2, 194);                                  // boundary 195 written
#undef COMPS
#undef COMP
}

// ---------------------------------------------------------------------------
// One recurrence step (~18 VALU), math unchanged (validated absmax 0.25).
// ---------------------------------------------------------------------------
#define STEP(P, TT, PE, QV)                                                   \
    {                                                                         \
        const float dfdt = fmaf(DF, (TT), ndftmx);                            \
        const float melt = __builtin_amdgcn_fmed3f(dfdt, s0, 0.0f);           \
        const float ps   = ((TT) <= TMN) ? (P) : 0.0f;                        \
        const float w    = melt - ps;                                         \
        s0 = s0 - w;                                                          \
        const float qs   = fmaxf(s1 - SM, 0.0f);                              \
        const float m    = fminf(s1, SM);                                     \
        const float u    = fmaf(g, s1, qc);                                   \
        const float qb   = fminf(QM, __builtin_amdgcn_exp2f(u));              \
        const float npei = (PE)*ninv_sm;                                      \
        const float A    = (s1 + ((P) + w)) - qs;                             \
        const float B    = fmaf(m, npei, A);                                  \
        s1 = fmaxf(B - qb, 0.0f);                                             \
        QV = qb + qs;                                                         \
    }

// ---------------------------------------------------------------------------
// Main chunked scan, LDS-staged. Cost model (r15/r16/r17 triangulated):
//   wall = max(steps/wave x C_lat(117cy), total_wave_steps x I / 1024 SIMDs)
// L=256, W=512 balances both terms (~37-42us): redundancy 3x (r17's W=3L was
// 4x and issue-bound at 55us), steps/wave=768 (r15's 1024 was latency-bound
// at 50us). ALIGNMENT INVARIANT: warm span = WARMCH*LBASE exactly, so
// s0b[chunk-WARMCH] (exact s0 at t=start) applies at start. Chunks 0-1 start
// at t=0 (exact prefix). W=512 validated r5/r9/r15: absmax == fully-serial.
// ---------------------------------------------------------------------------
__global__ __launch_bounds__(256)
void hydro_chunk_kernel(const float* __restrict__ x,
                        const float* __restrict__ s0b,
                        const float* __restrict__ f_,
                        const float* __restrict__ smax_,
                        const float* __restrict__ qmax_,
                        const float* __restrict__ df_,
                        const float* __restrict__ tmax_,
                        const float* __restrict__ tmin_,
                        float*       __restrict__ q) {
    __shared__ float4 sd[SDMAX];
    const int b     = blockIdx.x;          // 0..CHUNKS*2-1
    const int chunk = b >> 1;
    const int h     = ((b & 1) << 8) | (int)threadIdx.x;

    const float F   = f_[h];
    const float SM  = smax_[h];
    const float QM  = qmax_[h];
    const float DF  = df_[h];
    const float TMX = tmax_[h];
    const float TMN = tmin_[h];

    const float g       = F * 1.4426950408889634f;   // f * log2(e)
    const float qc      = __log2f(QM) - g * SM;       // log2(qmax) - g*smax
    const float ninv_sm = -1.0f / SM;
    const float ndftmx  = -(DF * TMX);

    const int cL    = chunk * LBASE;
    const int cE    = (cL + LBASE < T_STEPS) ? (cL + LBASE) : T_STEPS;
    const int start = (chunk >= WARMCH) ? (cL - WARM) : 0;  // boundary-aligned
    const int n     = cE - start;          // 256/512/768 (or 592 tail)

    for (int i = threadIdx.x; i < n; i += 256) {
        PET_FROM_X(start + i, p, tt, pe);
        sd[i] = make_float4(p, tt, pe, 0.f);
    }
    __syncthreads();

    float s0 = (chunk >= WARMCH) ? s0b[(chunk - WARMCH) * HID + h] : 0.0f;
    float s1 = 0.0f;

    const int nWarm16 = (cL - start) >> 4;            // 0, 16, or 32
    for (int it = 0; it < nWarm16; ++it) {
        const int base = it * 16;
        float qv;
#pragma unroll
        for (int i = 0; i < 16; ++i) {
            const float4 v = sd[base + i];
            STEP(v.x, v.y, v.z, qv);
        }
        (void)qv;
    }

    char* qbase  = (char*)q;
    unsigned off = (unsigned)cL * 2048u + (unsigned)h * 4u;
    const int wbase = cL - start;                     // 0, 256, or 512

    const int nOut16 = (cE - cL) >> 4;                // 16, or 5 for tail
    for (int it = 0; it < nOut16; ++it) {
        const int base = wbase + it * 16;
#pragma unroll
        for (int i = 0; i < 16; ++i) {
            const float4 v = sd[base + i];
            float qv;
            STEP(v.x, v.y, v.z, qv);
            *(float*)(qbase + off + (unsigned)i * 2048u) = qv;
        }
        off += 32768u;
    }
}

// ---------------------------------------------------------------------------
// Fallback: full-serial scan (correct for any ws_size), pet inline.
// ---------------------------------------------------------------------------
__global__ __launch_bounds__(64)
void hydro_serial_kernel(const float* __restrict__ x,
                         const float* __restrict__ f_,
                         const float* __restrict__ smax_,
                         const float* __restrict__ qmax_,
                         const float* __restrict__ df_,
                         const float* __restrict__ tmax_,
                         const float* __restrict__ tmin_,
                         float* __restrict__ q) {
    const int h = blockIdx.x * 64 + threadIdx.x;
    const float F = f_[h], SM = smax_[h], QM = qmax_[h];
    const float DF = df_[h], TMX = tmax_[h], TMN = tmin_[h];
    const float g       = F * 1.4426950408889634f;
    const float qc      = __log2f(QM) - g * SM;
    const float ninv_sm = -1.0f / SM;
    const float ndftmx  = -(DF * TMX);
    float s0 = 0.f, s1 = 0.f;
    for (int t = 0; t < T_STEPS; ++t) {
        PET_FROM_X(t, p, tt, pe);
        float qv;
        STEP(p, tt, pe, qv);
        q[(size_t)t * HID + h] = qv;
    }
}

// ---------------------------------------------------------------------------
extern "C" void kernel_launch(void* const* d_in, const int* in_sizes, int n_in,
                              void* d_out, int out_size, void* d_ws,
                              size_t ws_size, hipStream_t stream) {
    const float* x    = (const float*)d_in[0];
    const float* f    = (const float*)d_in[1];
    const float* smax = (const float*)d_in[2];
    const float* qmax = (const float*)d_in[3];
    const float* df   = (const float*)d_in[4];
    const float* tmax = (const float*)d_in[5];
    const float* tmin = (const float*)d_in[6];
    float* q = (float*)d_out;

    const size_t DM_BYTES  = (size_t)CHUNKS * HID * sizeof(double2); // ~1.6 MB
    const size_t S0B_OFF   = DM_BYTES;
    const size_t S0B_BYTES = (size_t)CHUNKS * HID * sizeof(float);   // ~400 KB
    const size_t NEED      = S0B_OFF + S0B_BYTES;

    if (ws_size >= NEED) {
        double2* dm  = (double2*)d_ws;
        float*   s0b = (float*)((char*)d_ws + S0B_OFF);

        lindley_agg_kernel<<<CHUNKS * 2, 256, 0, stream>>>(x, df, tmax, tmin, dm);
        lindley_scan_kernel<<<HID / 64, 64, 0, stream>>>(dm, s0b);
        hydro_chunk_kernel<<<CHUNKS * 2, 256, 0, stream>>>(
            x, s0b, f, smax, qmax, df, tmax, tmin, q);
    } else {
        hydro_serial_kernel<<<HID / 64, 64, 0, stream>>>(
            x, f, smax, qmax, df, tmax, tmin, q);
    }
}

// Round 19
// 69.965 us; speedup vs baseline: 1.8846x; 1.2552x over previous
//
#include <hip/hip_runtime.h>

#define T_STEPS 50000
#define HID     512
#define LBASE   400
#define CHUNKS  125            // 50000 = 125*400 exactly -> NO tail chunk
#define WARM    LBASE          // 400-step warmup (validated r6: absmax 0.25)
#define SDMAX   (WARM + LBASE) // 800 float4 = 12800 B LDS

static_assert(T_STEPS == CHUNKS * LBASE, "exact chunking");
static_assert(LBASE % 16 == 0, "16-step bodies");
static_assert(CHUNKS - 1 == 30 * 4 + 4, "scan rotation layout");

#define PIN2D(a) asm volatile("" : "+v"(a.x), "+v"(a.y))

// pet from raw x row (x is 600 KB -> L2-resident after first touch)
#define PET_FROM_X(t, P, TT, PE)                                              \
    const float P  = x[3 * (t) + 0];                                          \
    const float TT = x[3 * (t) + 1];                                          \
    const float ld_##P = x[3 * (t) + 2];                                      \
    const float esat_##P = 0.611f * __expf(17.3f * TT / (TT + 237.3f));       \
    const float PE = 29.8f * (ld_##P * 24.0f) * esat_##P / (TT + 273.2f);

// ---------------------------------------------------------------------------
// One recurrence step (~18 VALU), math unchanged (validated absmax 0.25).
// ---------------------------------------------------------------------------
#define STEP(P, TT, PE, QV)                                                   \
    {                                                                         \
        const float dfdt = fmaf(DF, (TT), ndftmx);                            \
        const float melt = __builtin_amdgcn_fmed3f(dfdt, s0, 0.0f);           \
        const float ps   = ((TT) <= TMN) ? (P) : 0.0f;                        \
        const float w    = melt - ps;                                         \
        s0 = s0 - w;                                                          \
        const float qs   = fmaxf(s1 - SM, 0.0f);                              \
        const float m    = fminf(s1, SM);                                     \
        const float u    = fmaf(g, s1, qc);                                   \
        const float qb   = fminf(QM, __builtin_amdgcn_exp2f(u));              \
        const float npei = (PE)*ninv_sm;                                      \
        const float A    = (s1 + ((P) + w)) - qs;                             \
        const float B    = fmaf(m, npei, A);                                  \
        s1 = fmaxf(B - qb, 0.0f);                                             \
        QV = qb + qs;                                                         \
    }

// 16-step body: all 16 LDS reads issued into NAMED registers before any STEP
// (independent -> one latency wait per body, arrivals pipelined under the
// serial STEP chain). DOSTORE(i) is empty for warmup bodies.
#define STEP16_BODY(base, DOSTORE)                                            \
    {                                                                         \
        const float4 w0  = sd[(base) + 0],  w1  = sd[(base) + 1];             \
        const float4 w2  = sd[(base) + 2],  w3  = sd[(base) + 3];             \
        const float4 w4  = sd[(base) + 4],  w5  = sd[(base) + 5];             \
        const float4 w6  = sd[(base) + 6],  w7  = sd[(base) + 7];             \
        const float4 w8  = sd[(base) + 8],  w9  = sd[(base) + 9];             \
        const float4 w10 = sd[(base) + 10], w11 = sd[(base) + 11];            \
        const float4 w12 = sd[(base) + 12], w13 = sd[(base) + 13];            \
        const float4 w14 = sd[(base) + 14], w15 = sd[(base) + 15];            \
        float qv;                                                             \
        STEP(w0.x,  w0.y,  w0.z,  qv); DOSTORE(0);                            \
        STEP(w1.x,  w1.y,  w1.z,  qv); DOSTORE(1);                            \
        STEP(w2.x,  w2.y,  w2.z,  qv); DOSTORE(2);                            \
        STEP(w3.x,  w3.y,  w3.z,  qv); DOSTORE(3);                            \
        STEP(w4.x,  w4.y,  w4.z,  qv); DOSTORE(4);                            \
        STEP(w5.x,  w5.y,  w5.z,  qv); DOSTORE(5);                            \
        STEP(w6.x,  w6.y,  w6.z,  qv); DOSTORE(6);                            \
        STEP(w7.x,  w7.y,  w7.z,  qv); DOSTORE(7);                            \
        STEP(w8.x,  w8.y,  w8.z,  qv); DOSTORE(8);                            \
        STEP(w9.x,  w9.y,  w9.z,  qv); DOSTORE(9);                            \
        STEP(w10.x, w10.y, w10.z, qv); DOSTORE(10);                           \
        STEP(w11.x, w11.y, w11.z, qv); DOSTORE(11);                           \
        STEP(w12.x, w12.y, w12.z, qv); DOSTORE(12);                           \
        STEP(w13.x, w13.y, w13.z, qv); DOSTORE(13);                           \
        STEP(w14.x, w14.y, w14.z, qv); DOSTORE(14);                           \
        STEP(w15.x, w15.y, w15.z, qv); DOSTORE(15);                           \
    }
#define NOSTORE(i)
#define QSTORE(i) *(float*)(qbase + off + (unsigned)(i) * 2048u) = qv

// ---------------------------------------------------------------------------
// Pass A: snow bucket is max-plus linear (Lindley): s0' = max(s0 + d, ps),
// d = ps - cap, cap = max(df*(t-tmax), 0). Segment (D, M) composes as
// x -> max(x + D, M). Block = chunk x 256 units; pet inline into LDS.
// ---------------------------------------------------------------------------
__global__ __launch_bounds__(256, 1)
void lindley_agg_kernel(const float* __restrict__ x,
                        const float* __restrict__ df_,
                        const float* __restrict__ tmax_,
                        const float* __restrict__ tmin_,
                        double2* __restrict__ dm) {
    __shared__ float4 sd[LBASE];
    const int b     = blockIdx.x;          // 0..CHUNKS*2-1
    const int chunk = b >> 1;
    const int h     = ((b & 1) << 8) | (int)threadIdx.x;

    const float DF = df_[h], TMX = tmax_[h], TMN = tmin_[h];
    const float ndftmx = -(DF * TMX);

    const int cL = chunk * LBASE;
    for (int i = threadIdx.x; i < LBASE; i += 256) {
        PET_FROM_X(cL + i, p, tt, pe);
        sd[i] = make_float4(p, tt, pe, 0.f);
    }
    __syncthreads();

    double D = 0.0, M = -1.0e300;
    for (int it = 0; it < LBASE / 16; ++it) {
        const int base = it * 16;
#pragma unroll
        for (int i = 0; i < 16; ++i) {
            const float4 v = sd[base + i];
            const float cap = fmaxf(fmaf(DF, v.y, ndftmx), 0.0f);
            const float ps  = (v.y <= TMN) ? v.x : 0.0f;
            const double d  = (double)ps - (double)cap;
            D += d;
            M = fmax(M + d, (double)ps);
        }
    }
    dm[chunk * HID + h] = make_double2(D, M);
}

// ---------------------------------------------------------------------------
// Pass B: compose the 125 chunk maps sequentially per unit -> EXACT s0 at
// every boundary. Depth-4 rotating prefetch; 124 composes = 30*4 + 4, and
// the last reload reads dm[123] -> no over-read at all.
// ---------------------------------------------------------------------------
__global__ __launch_bounds__(64)
void lindley_scan_kernel(const double2* __restrict__ dm,
                         float* __restrict__ s0b) {
    const int h = blockIdx.x * 64 + threadIdx.x;   // grid = 8 blocks
    const double2* dp = dm + h;
    double xv = 0.0;
    s0b[h] = 0.0f;                                  // boundary 0: s0 = 0

#define COMP(a, c)                                                            \
    {                                                                         \
        PIN2D(a);                                                             \
        xv = fmax(xv + a.x, a.y);                                             \
        s0b[(size_t)((c) + 1) * HID + h] = (float)xv;                         \
    }
#define COMPS(PJ, c)                                                          \
    { COMP(PJ, c); PJ = dp[(size_t)((c) + 4) * HID]; }

    double2 p0 = dp[0];
    double2 p1 = dp[(size_t)1 * HID];
    double2 p2 = dp[(size_t)2 * HID];
    double2 p3 = dp[(size_t)3 * HID];

    for (int j = 0; j < 30; ++j) {                  // composes 0..119
        const int c = 4 * j;
        COMPS(p0, c);
        COMPS(p1, c + 1);
        COMPS(p2, c + 2);
        COMPS(p3, c + 3);                           // j=29 reloads dm[123]: ok
    }
    COMP(p0, 120);
    COMP(p1, 121);
    COMP(p2, 122);
    COMP(p3, 123);                                  // boundary 124 written
#undef COMPS
#undef COMP
}

// ---------------------------------------------------------------------------
// Main chunked scan, LDS-staged, k=1 regime. r15/r17/r18 isolate the law:
// co-resident waves ADD ~78cy/step instead of hiding latency (117->195->341),
// so run EXACTLY 1 block/CU (250 blocks <= 256) and minimize steps/wave:
// L=W=400 (r6-validated: absmax == fully-serial) -> 800 steps/wave.
// ALIGNMENT INVARIANT: warm span = LBASE exactly, so s0b[chunk-1] (exact s0
// at t=start) applies at start. Chunk 0 starts at t=0 (fully exact).
// ---------------------------------------------------------------------------
__global__ __launch_bounds__(256, 1)
void hydro_chunk_kernel(const float* __restrict__ x,
                        const float* __restrict__ s0b,
                        const float* __restrict__ f_,
                        const float* __restrict__ smax_,
                        const float* __restrict__ qmax_,
                        const float* __restrict__ df_,
                        const float* __restrict__ tmax_,
                        const float* __restrict__ tmin_,
                        float*       __restrict__ q) {
    __shared__ float4 sd[SDMAX];
    const int b     = blockIdx.x;          // 0..CHUNKS*2-1
    const int chunk = b >> 1;
    const int h     = ((b & 1) << 8) | (int)threadIdx.x;

    const float F   = f_[h];
    const float SM  = smax_[h];
    const float QM  = qmax_[h];
    const float DF  = df_[h];
    const float TMX = tmax_[h];
    const float TMN = tmin_[h];

    const float g       = F * 1.4426950408889634f;   // f * log2(e)
    const float qc      = __log2f(QM) - g * SM;       // log2(qmax) - g*smax
    const float ninv_sm = -1.0f / SM;
    const float ndftmx  = -(DF * TMX);

    const int cL    = chunk * LBASE;
    const int start = (chunk >= 1) ? (cL - WARM) : 0;   // boundary-aligned
    const int n     = (chunk >= 1) ? (WARM + LBASE) : LBASE;

    for (int i = threadIdx.x; i < n; i += 256) {
        PET_FROM_X(start + i, p, tt, pe);
        sd[i] = make_float4(p, tt, pe, 0.f);
    }
    __syncthreads();

    float s0 = (chunk >= 1) ? s0b[(chunk - 1) * HID + h] : 0.0f;
    float s1 = 0.0f;

    const int nWarm16 = (cL - start) >> 4;            // 0 or 25
    for (int it = 0; it < nWarm16; ++it) {
        STEP16_BODY(it * 16, NOSTORE);
    }

    char* qbase  = (char*)q;
    unsigned off = (unsigned)cL * 2048u + (unsigned)h * 4u;
    const int wbase = cL - start;                     // 0 or 400

    for (int it = 0; it < LBASE / 16; ++it) {         // 25 output bodies
        STEP16_BODY(wbase + it * 16, QSTORE);
        off += 32768u;
    }
}

// ---------------------------------------------------------------------------
// Fallback: full-serial scan (correct for any ws_size), pet inline.
// ---------------------------------------------------------------------------
__global__ __launch_bounds__(64)
void hydro_serial_kernel(const float* __restrict__ x,
                         const float* __restrict__ f_,
                         const float* __restrict__ smax_,
                         const float* __restrict__ qmax_,
                         const float* __restrict__ df_,
                         const float* __restrict__ tmax_,
                         const float* __restrict__ tmin_,
                         float* __restrict__ q) {
    const int h = blockIdx.x * 64 + threadIdx.x;
    const float F = f_[h], SM = smax_[h], QM = qmax_[h];
    const float DF = df_[h], TMX = tmax_[h], TMN = tmin_[h];
    const float g       = F * 1.4426950408889634f;
    const float qc      = __log2f(QM) - g * SM;
    const float ninv_sm = -1.0f / SM;
    const float ndftmx  = -(DF * TMX);
    float s0 = 0.f, s1 = 0.f;
    for (int t = 0; t < T_STEPS; ++t) {
        PET_FROM_X(t, p, tt, pe);
        float qv;
        STEP(p, tt, pe, qv);
        q[(size_t)t * HID + h] = qv;
    }
}

// ---------------------------------------------------------------------------
extern "C" void kernel_launch(void* const* d_in, const int* in_sizes, int n_in,
                              void* d_out, int out_size, void* d_ws,
                              size_t ws_size, hipStream_t stream) {
    const float* x    = (const float*)d_in[0];
    const float* f    = (const float*)d_in[1];
    const float* smax = (const float*)d_in[2];
    const float* qmax = (const float*)d_in[3];
    const float* df   = (const float*)d_in[4];
    const float* tmax = (const float*)d_in[5];
    const float* tmin = (const float*)d_in[6];
    float* q = (float*)d_out;

    const size_t DM_BYTES  = (size_t)CHUNKS * HID * sizeof(double2); // ~1.0 MB
    const size_t S0B_OFF   = DM_BYTES;
    const size_t S0B_BYTES = (size_t)CHUNKS * HID * sizeof(float);   // ~256 KB
    const size_t NEED      = S0B_OFF + S0B_BYTES;

    if (ws_size >= NEED) {
        double2* dm  = (double2*)d_ws;
        float*   s0b = (float*)((char*)d_ws + S0B_OFF);

        lindley_agg_kernel<<<CHUNKS * 2, 256, 0, stream>>>(x, df, tmax, tmin, dm);
        lindley_scan_kernel<<<HID / 64, 64, 0, stream>>>(dm, s0b);
        hydro_chunk_kernel<<<CHUNKS * 2, 256, 0, stream>>>(
            x, s0b, f, smax, qmax, df, tmax, tmin, q);
    } else {
        hydro_serial_kernel<<<HID / 64, 64, 0, stream>>>(
            x, f, smax, qmax, df, tmax, tmin, q);
    }
}